// Round 3
// baseline (13880.519 us; speedup 1.0000x reference)
//
#include <hip/hip_runtime.h>
#include <stdint.h>
#include <stddef.h>

// WindowAttention fused kernel (Swin window MHA).
// Inputs fp32, OUTPUT fp32 (reference dtype). Internally x staged as bf16.
// B=8, H=W=128, C=512, WS=8 -> 2048 windows of 64 tokens; NH=16, hd=32.
// One workgroup (256 threads) per window; zero global workspace.

typedef unsigned short ushort_t;
typedef __attribute__((ext_vector_type(8))) unsigned short ushort8;

#define N_TOK 64
#define XS_STRIDE 520   // 512 + 8 bf16 pad
#define AO_STRIDE 520
#define QLS_STRIDE 36   // 32 + 4 fp32 pad, keeps float4 alignment

__device__ __forceinline__ float bf2f(unsigned short u) {
    union { unsigned int i; float f; } x;
    x.i = ((unsigned int)u) << 16;
    return x.f;
}
__device__ __forceinline__ unsigned short f2bf(float f) {
    union { float f; unsigned int i; } x;
    x.f = f;
    unsigned int r = x.i + 0x7fffu + ((x.i >> 16) & 1u);  // round-nearest-even
    return (unsigned short)(r >> 16);
}

__global__ __launch_bounds__(256, 1)
void swin_window_attn(const float* __restrict__ xg,
                      const float* __restrict__ qkv_w,
                      const float* __restrict__ qkv_b,
                      const float* __restrict__ proj_w,
                      const float* __restrict__ proj_b,
                      const float* __restrict__ btab,
                      float* __restrict__ outg)
{
    extern __shared__ char smem[];
    ushort_t* xs = (ushort_t*)smem;                 // [64][520] bf16  = 66560 B
    ushort_t* ao = xs + N_TOK * XS_STRIDE;          // [64][520] bf16  = 66560 B
    char* scratch = (char*)(ao + N_TOK * AO_STRIDE);
    // scratch overlays (time-multiplexed, 27648 B):
    float* wls = (float*)scratch;                   // [64][96] fp32 qkv-w chunk (24576 B)
    float* qq  = (float*)scratch;                   // [64][36] fp32 Q
    float* kk  = qq + N_TOK * QLS_STRIDE;           // [64][36] fp32 K
    float* vvb = kk + N_TOK * QLS_STRIDE;           // [64][36] fp32 V  (total 27648 B)
    float* pls = (float*)scratch;                   // [64][64] fp32 proj-w chunk (16384 B)

    const int tid = threadIdx.x;
    const int blk = blockIdx.x;          // 0..2047
    const int b   = blk >> 8;
    const int wy  = (blk >> 4) & 15;
    const int wx  = blk & 15;

    // ---- stage x window (64 tokens x 512 ch, fp32) into LDS as bf16 ----
    for (int l = 0; l < 16; ++l) {
        int idx = l * 256 + tid;         // 0..4095 chunks of 8 floats
        int t   = idx >> 6;              // token 0..63
        int v   = idx & 63;              // 8-float chunk within row
        int ty = t >> 3, tx = t & 7;
        size_t goff = ((size_t)((b * 128 + wy * 8 + ty) * 128 + wx * 8 + tx)) * 512 + v * 8;
        float4 a0 = *(const float4*)(xg + goff);
        float4 a1 = *(const float4*)(xg + goff + 4);
        ushort8 d;
        d[0] = f2bf(a0.x); d[1] = f2bf(a0.y); d[2] = f2bf(a0.z); d[3] = f2bf(a0.w);
        d[4] = f2bf(a1.x); d[5] = f2bf(a1.y); d[6] = f2bf(a1.z); d[7] = f2bf(a1.w);
        *(ushort8*)(xs + t * XS_STRIDE + v * 8) = d;
    }
    __syncthreads();

    const int t  = tid >> 2;             // token / attention row
    const int dg = tid & 3;              // d-group (8 dims each) / softmax sub-lane
    const float scale = 0.17677669529663687f;   // 1/sqrt(32)

    // ================= per-head: QKV -> attention -> ao =================
    for (int h = 0; h < 16; ++h) {
        float acc0[8], acc1[8], acc2[8];
        #pragma unroll
        for (int k = 0; k < 8; ++k) { acc0[k] = 0.f; acc1[k] = 0.f; acc2[k] = 0.f; }

        for (int cc = 0; cc < 8; ++cc) {          // K-chunks of 64
            // stage qkv_w rows [cc*64, cc*64+64), cols {s*512 + h*32 + d} fp32
            #pragma unroll
            for (int l = 0; l < 3; ++l) {
                int idx = l * 256 + tid;          // 0..767 = 64 rows * 12 vec8
                int r = idx / 12;
                int g = idx % 12;
                int s  = g >> 2;
                int d8 = (g & 3) * 8;
                const float* src = qkv_w + (size_t)(cc * 64 + r) * 1536 + s * 512 + h * 32 + d8;
                float4 w0 = *(const float4*)(src);
                float4 w1 = *(const float4*)(src + 4);
                float* dst = wls + r * 96 + s * 32 + d8;
                *(float4*)(dst)     = w0;
                *(float4*)(dst + 4) = w1;
            }
            __syncthreads();

            for (int cg = 0; cg < 8; ++cg) {
                ushort8 xv8 = *(const ushort8*)(xs + t * XS_STRIDE + cc * 64 + cg * 8);
                #pragma unroll
                for (int j = 0; j < 8; ++j) {
                    float xv = bf2f(xv8[j]);
                    const float* wr = wls + (cg * 8 + j) * 96 + dg * 8;
                    #pragma unroll
                    for (int k = 0; k < 8; ++k) {
                        acc0[k] += xv * wr[k];        // q
                        acc1[k] += xv * wr[32 + k];   // k
                        acc2[k] += xv * wr[64 + k];   // v
                    }
                }
            }
            __syncthreads();
        }

        // bias (+ fold attention scale into q), then park Q/K/V in LDS fp32
        #pragma unroll
        for (int k = 0; k < 8; ++k) {
            acc0[k] = (acc0[k] + qkv_b[          h * 32 + dg * 8 + k]) * scale;
            acc1[k] =  acc1[k] + qkv_b[ 512 +    h * 32 + dg * 8 + k];
            acc2[k] =  acc2[k] + qkv_b[1024 +    h * 32 + dg * 8 + k];
        }
        #pragma unroll
        for (int k = 0; k < 8; ++k) {
            qq [t * QLS_STRIDE + dg * 8 + k] = acc0[k];
            kk [t * QLS_STRIDE + dg * 8 + k] = acc1[k];
            vvb[t * QLS_STRIDE + dg * 8 + k] = acc2[k];
        }
        __syncthreads();

        // ---- S = Q K^T + bias, row softmax; 4 lanes per row, 16 cols each ----
        const int row = t;
        const int sub = dg;
        float qr[32];
        #pragma unroll
        for (int d = 0; d < 32; d += 4) {
            float4 qv = *(const float4*)(qq + row * QLS_STRIDE + d);
            qr[d] = qv.x; qr[d+1] = qv.y; qr[d+2] = qv.z; qr[d+3] = qv.w;
        }
        float sv[16];
        #pragma unroll
        for (int mi = 0; mi < 16; ++mi) {
            int m = mi * 4 + sub;                 // interleaved -> conflict-free K reads
            float dot = 0.f;
            #pragma unroll
            for (int d = 0; d < 32; d += 4) {
                float4 kv = *(const float4*)(kk + m * QLS_STRIDE + d);
                dot += qr[d]*kv.x + qr[d+1]*kv.y + qr[d+2]*kv.z + qr[d+3]*kv.w;
            }
            int dy = (row >> 3) - (m >> 3) + 7;   // Swin relative index
            int dx = (row & 7)  - (m & 7)  + 7;
            sv[mi] = dot + btab[(dy * 15 + dx) * 16 + h];
        }
        float mx = sv[0];
        #pragma unroll
        for (int mi = 1; mi < 16; ++mi) mx = fmaxf(mx, sv[mi]);
        mx = fmaxf(mx, __shfl_xor(mx, 1));
        mx = fmaxf(mx, __shfl_xor(mx, 2));
        float sum = 0.f;
        #pragma unroll
        for (int mi = 0; mi < 16; ++mi) { sv[mi] = __expf(sv[mi] - mx); sum += sv[mi]; }
        sum += __shfl_xor(sum, 1);
        sum += __shfl_xor(sum, 2);
        float inv = 1.0f / sum;
        #pragma unroll
        for (int mi = 0; mi < 16; ++mi) sv[mi] *= inv;

        // ---- O = P V : partial over this lane's 16 cols, reduce across 4 lanes ----
        float ov[32];
        #pragma unroll
        for (int d = 0; d < 32; ++d) ov[d] = 0.f;
        #pragma unroll
        for (int mi = 0; mi < 16; ++mi) {
            int m = mi * 4 + sub;
            float p = sv[mi];
            #pragma unroll
            for (int d = 0; d < 32; d += 4) {
                float4 vv4 = *(const float4*)(vvb + m * QLS_STRIDE + d);
                ov[d] += p * vv4.x; ov[d+1] += p * vv4.y; ov[d+2] += p * vv4.z; ov[d+3] += p * vv4.w;
            }
        }
        #pragma unroll
        for (int d = 0; d < 32; ++d) {
            ov[d] += __shfl_xor(ov[d], 1);
            ov[d] += __shfl_xor(ov[d], 2);
        }
        ushort8 o8;
        #pragma unroll
        for (int k = 0; k < 8; ++k) o8[k] = f2bf(ov[sub * 8 + k]);
        *(ushort8*)(ao + row * AO_STRIDE + h * 32 + sub * 8) = o8;
        __syncthreads();   // qq/kk/vvb reads done before next head re-stages wls
    }

    // ================= proj GEMM + window reverse (fp32 output) =================
    const int ty = t >> 3, tx = t & 7;
    float* orow = outg + ((size_t)((b * 128 + wy * 8 + ty) * 128 + wx * 8 + tx)) * 512;

    for (int coc = 0; coc < 8; ++coc) {          // 64 output cols per pass
        float pacc[16];
        #pragma unroll
        for (int k = 0; k < 16; ++k) pacc[k] = 0.f;
        for (int cic = 0; cic < 8; ++cic) {      // K-chunks of 64
            #pragma unroll
            for (int l = 0; l < 2; ++l) {
                int idx = l * 256 + tid;          // 0..511 = 64 rows * 8 vec8
                int r = idx >> 3;
                int g = idx & 7;
                const float* src = proj_w + (size_t)(cic * 64 + r) * 512 + coc * 64 + g * 8;
                float4 w0 = *(const float4*)(src);
                float4 w1 = *(const float4*)(src + 4);
                float* dst = pls + r * 64 + g * 8;
                *(float4*)(dst)     = w0;
                *(float4*)(dst + 4) = w1;
            }
            __syncthreads();

            for (int cg = 0; cg < 8; ++cg) {
                ushort8 a8 = *(const ushort8*)(ao + t * AO_STRIDE + cic * 64 + cg * 8);
                #pragma unroll
                for (int j = 0; j < 8; ++j) {
                    float av = bf2f(a8[j]);
                    const float* wr = pls + (cg * 8 + j) * 64 + dg * 16;
                    #pragma unroll
                    for (int k = 0; k < 16; ++k) pacc[k] += av * wr[k];
                }
            }
            __syncthreads();
        }
        #pragma unroll
        for (int q4 = 0; q4 < 4; ++q4) {
            float4 o;
            o.x = pacc[q4 * 4 + 0] + proj_b[coc * 64 + dg * 16 + q4 * 4 + 0];
            o.y = pacc[q4 * 4 + 1] + proj_b[coc * 64 + dg * 16 + q4 * 4 + 1];
            o.z = pacc[q4 * 4 + 2] + proj_b[coc * 64 + dg * 16 + q4 * 4 + 2];
            o.w = pacc[q4 * 4 + 3] + proj_b[coc * 64 + dg * 16 + q4 * 4 + 3];
            *(float4*)(orow + coc * 64 + dg * 16 + q4 * 4) = o;
        }
    }
}

extern "C" void kernel_launch(void* const* d_in, const int* in_sizes, int n_in,
                              void* d_out, int out_size, void* d_ws, size_t ws_size,
                              hipStream_t stream) {
    const float* x      = (const float*)d_in[0];
    const float* qkv_w  = (const float*)d_in[1];
    const float* qkv_b  = (const float*)d_in[2];
    const float* proj_w = (const float*)d_in[3];
    const float* proj_b = (const float*)d_in[4];
    const float* btab   = (const float*)d_in[5];
    float* out = (float*)d_out;

    // LDS: 66560 (xs) + 66560 (ao) + 27648 (scratch) = 160768 B <= 160 KiB
    const size_t smem = (size_t)(N_TOK * XS_STRIDE * 2 + N_TOK * AO_STRIDE * 2
                                 + 3 * N_TOK * QLS_STRIDE * 4);
    dim3 grid(2048), block(256);
    hipLaunchKernelGGL(swin_window_attn, grid, block, smem, stream,
                       x, qkv_w, qkv_b, proj_w, proj_b, btab, out);
}